// Round 1
// baseline (143.230 us; speedup 1.0000x reference)
//
#include <hip/hip_runtime.h>
#include <hip/hip_bf16.h>

// Problem geometry (fixed by reference config)
#define IN_F   4096
#define OUT_F  12288
#define OUT_PG 4096
#define M_ROWS 1024     // 2*512
#define R2     32       // GROUPS * R = 2*16

// ---------------- Kernel A: T[m][r32] = sum_k x[m][k] * wA[r32][k] ----------------
// Grid: (IN_F/KT = 64 k-tiles, M_ROWS/RT = 4 row-tiles), 256 threads.
// Per block: stage A tile (32 x KT) in LDS, thread tile = 8 rows x 4 r.
// Epilogue: atomicAdd partial sums into T (T pre-zeroed via memsetAsync).
#define KT 64
#define RT 256

__global__ __launch_bounds__(256) void lora_a_kernel(
    const float* __restrict__ x, const float* __restrict__ wA,
    float* __restrict__ T) {
  __shared__ float As[R2][KT + 4];   // pad 4 floats (16B) -> stride 272B, 16B-aligned
  const int t = threadIdx.x;
  const int kbase = blockIdx.x * KT;
  const int rbase = blockIdx.y * RT;

  // Stage A tile: 32*64 = 2048 floats, 8 per thread (2x float4), coalesced.
  {
    const int f0 = t * 4;
#pragma unroll
    for (int i = 0; i < 2; ++i) {
      const int ff = f0 + i * 1024;
      const int r  = ff >> 6;     // /KT
      const int kk = ff & (KT - 1);
      const float4 v = *reinterpret_cast<const float4*>(&wA[r * IN_F + kbase + kk]);
      *reinterpret_cast<float4*>(&As[r][kk]) = v;
    }
  }
  __syncthreads();

  const int rg = t & 7;    // r = rg*4 + c, c in [0,4)
  const int wg = t >> 3;   // rows = rbase + wg + i*32, i in [0,8)

  float acc[8][4];
#pragma unroll
  for (int i = 0; i < 8; ++i)
#pragma unroll
    for (int c = 0; c < 4; ++c) acc[i][c] = 0.f;

  for (int kk = 0; kk < KT; kk += 4) {
    float4 a[4];
#pragma unroll
    for (int c = 0; c < 4; ++c)
      a[c] = *reinterpret_cast<const float4*>(&As[rg * 4 + c][kk]);
#pragma unroll
    for (int i = 0; i < 8; ++i) {
      const int row = rbase + wg + i * 32;
      const float4 xv = *reinterpret_cast<const float4*>(&x[row * IN_F + kbase + kk]);
#pragma unroll
      for (int c = 0; c < 4; ++c) {
        acc[i][c] += xv.x * a[c].x + xv.y * a[c].y + xv.z * a[c].z + xv.w * a[c].w;
      }
    }
  }

#pragma unroll
  for (int i = 0; i < 8; ++i) {
    const int row = rbase + wg + i * 32;
#pragma unroll
    for (int c = 0; c < 4; ++c)
      atomicAdd(&T[row * R2 + rg * 4 + c], acc[i][c]);
  }
}

// ---------------- Kernel B: out[m][col] = sum_r T[m][g*16+r] * wB[(g*4096+j)*16+r] ----
// Grid: (OUT_F/256 = 48 col-blocks, M_ROWS/16 = 64 row-blocks), 256 threads.
// outblk = colblock>>4 in {0,1,2}; outblk==1 writes zeros.
// Thread tile: 4 rows x 4 consecutive cols (float4 stores).
__global__ __launch_bounds__(256) void lora_b_kernel(
    const float* __restrict__ T, const float* __restrict__ wB,
    float* __restrict__ out) {
  const int t = threadIdx.x;
  const int bx = blockIdx.x;          // 0..47
  const int by = blockIdx.y;          // 0..63
  const int cbase = bx << 8;          // col base (256 cols per block)
  const int rbase = by << 4;          // row base (16 rows per block)
  const int outblk = bx >> 4;         // 0,1,2
  const int cq = t & 63;              // col quad index
  const int rg = t >> 6;              // wave id = row group (wave-uniform)

  if (outblk == 1) {
    const float4 z = {0.f, 0.f, 0.f, 0.f};
#pragma unroll
    for (int rr = 0; rr < 4; ++rr) {
      const int row = rbase + rg * 4 + rr;
      *reinterpret_cast<float4*>(&out[row * OUT_F + cbase + cq * 4]) = z;
    }
    return;
  }
  const int g = (outblk == 0) ? 0 : 1;

  __shared__ float Ts[16][16];
  if (t < 64) {
    const int row = t >> 2, q = t & 3;
    *reinterpret_cast<float4*>(&Ts[row][q * 4]) =
        *reinterpret_cast<const float4*>(&T[(rbase + row) * R2 + g * 16 + q * 4]);
  }
  __syncthreads();

  const int j = cbase - ((outblk == 2) ? 8192 : 0) + cq * 4;  // within-group col base
  const float* Bp = &wB[(g * OUT_PG + j) * 16];

  // B rows for the 4 cols: 256B contiguous per thread.
  float4 B[4][4];
#pragma unroll
  for (int c = 0; c < 4; ++c)
#pragma unroll
    for (int q = 0; q < 4; ++q)
      B[c][q] = *reinterpret_cast<const float4*>(&Bp[c * 16 + q * 4]);

#pragma unroll
  for (int rr = 0; rr < 4; ++rr) {
    const int rowl = rg * 4 + rr;
    float4 tv[4];
#pragma unroll
    for (int q = 0; q < 4; ++q)
      tv[q] = *reinterpret_cast<const float4*>(&Ts[rowl][q * 4]);
    float4 accv;
    float* accp = reinterpret_cast<float*>(&accv);
#pragma unroll
    for (int c = 0; c < 4; ++c) {
      float s = 0.f;
#pragma unroll
      for (int q = 0; q < 4; ++q) {
        s += tv[q].x * B[c][q].x + tv[q].y * B[c][q].y +
             tv[q].z * B[c][q].z + tv[q].w * B[c][q].w;
      }
      accp[c] = s;
    }
    *reinterpret_cast<float4*>(&out[(rbase + rowl) * OUT_F + cbase + cq * 4]) = accv;
  }
}

extern "C" void kernel_launch(void* const* d_in, const int* in_sizes, int n_in,
                              void* d_out, int out_size, void* d_ws, size_t ws_size,
                              hipStream_t stream) {
  const float* x  = (const float*)d_in[0];   // (2,512,4096) f32
  const float* wA = (const float*)d_in[1];   // (32,4096) f32
  const float* wB = (const float*)d_in[2];   // (8192,16) f32
  float* out = (float*)d_out;                // (2,512,12288) f32
  float* T   = (float*)d_ws;                 // (1024,32) f32 scratch

  hipMemsetAsync(T, 0, M_ROWS * R2 * sizeof(float), stream);
  lora_a_kernel<<<dim3(IN_F / KT, M_ROWS / RT), 256, 0, stream>>>(x, wA, T);
  lora_b_kernel<<<dim3(OUT_F / 256, M_ROWS / 16), 256, 0, stream>>>(T, wB, out);
}